// Round 6
// baseline (1666.719 us; speedup 1.0000x reference)
//
#include <hip/hip_runtime.h>
#include <hip/hip_bf16.h>

typedef __hip_bfloat16 bf16;
typedef __attribute__((ext_vector_type(8))) short short8;
typedef __attribute__((ext_vector_type(4))) short short4v;
typedef __attribute__((ext_vector_type(4))) float f32x4;

#define DEVINL static __device__ __forceinline__

DEVINL float b2f(bf16 x) { return __bfloat162float(x); }
DEVINL bf16 f2b(float x) { return __float2bfloat16(x); }
DEVINL float sb2f(short s) { return b2f(__builtin_bit_cast(bf16, s)); }
DEVINL short f2sb(float x) { return __builtin_bit_cast(short, f2b(x)); }

DEVINL void gload16(const void* g, void* l) {
  __builtin_amdgcn_global_load_lds(
      (const __attribute__((address_space(1))) void*)g,
      (__attribute__((address_space(3))) void*)l, 16, 0, 0);
}

DEVINL float wave_sum(float v) {
#pragma unroll
  for (int o = 32; o > 0; o >>= 1) v += __shfl_down(v, o, 64);
  return v;
}

DEVINL float wave_allsum(float v) {
#pragma unroll
  for (int o = 32; o > 0; o >>= 1) v += __shfl_xor(v, o, 64);
  return v;
}

// Exact-erf GELU via Abramowitz-Stegun 7.1.26 (max abs err 1.5e-7 in erf,
// far below bf16 output rounding).
DEVINL float gelu_exact(float v) {
  const float z = v * 0.70710678118654752f;
  const float az = fabsf(z);
  const float t = 1.0f / (1.0f + 0.3275911f * az);
  float p = 1.061405429f;
  p = p * t - 1.453152027f;
  p = p * t + 1.421413741f;
  p = p * t - 0.284496736f;
  p = p * t + 0.254829592f;
  const float e = __expf(-z * z);
  const float erf_az = 1.0f - p * t * e;
  const float er = (z < 0.f) ? -erf_az : erf_az;
  return 0.5f * v * (1.0f + er);
}

#define BARRIER()                             \
  do {                                        \
    __asm__ __volatile__("" ::: "memory");    \
    __builtin_amdgcn_s_barrier();             \
    __asm__ __volatile__("" ::: "memory");    \
  } while (0)
#define WAIT_LGKM0() __asm__ __volatile__("s_waitcnt lgkmcnt(0)" ::: "memory")
#define WAIT_VM(n) __asm__ __volatile__("s_waitcnt vmcnt(" #n ")" ::: "memory")

// ---------------------------------------------------------------------------
// Legacy NT GEMM (64-tile) — retained for the Newton-Schulz chain only.
// MODE 3: split-write hi/lo bf16 (NS gram)   MODE 4: NS update
// ---------------------------------------------------------------------------
template <int MODE, bool SPLIT, int BM>
__global__ __launch_bounds__(256) void gemm_nt(
    const bf16* __restrict__ A0, const bf16* __restrict__ A1,
    const bf16* __restrict__ B0, const bf16* __restrict__ B1,
    int K, int lda, int ldb, long bsA, long bsB, long bsC,
    float alpha, float beta, float* __restrict__ Xf,
    bf16* __restrict__ Whi, bf16* __restrict__ Wlo,
    bf16* __restrict__ Thi, bf16* __restrict__ Tlo) {
  constexpr int BK = 64;
  constexpr int MT = BM / 32;
  constexpr int NLOAD = BM * BK / 2048;
  extern __shared__ char smem[];
  bf16* AsH = (bf16*)smem;
  bf16* BsH = AsH + BM * BK;
  bf16* AsL = BsH + BM * BK;
  bf16* BsL = AsL + BM * BK;

  const int t = threadIdx.x;
  const int lane = t & 63, w = t >> 6;
  const long bz = blockIdx.z;
  const bf16* Ab0 = A0 + bz * bsA;
  const bf16* Bb0 = B0 + bz * bsB;
  const bf16* Ab1 = SPLIT ? (A1 + bz * bsA) : nullptr;
  const bf16* Bb1 = SPLIT ? (B1 + bz * bsB) : nullptr;

  const int row0 = blockIdx.x * BM, col0 = blockIdx.y * BM;
  const int wm = (w >> 1) * (BM / 2), wn = (w & 1) * (BM / 2);
  const int jj = lane >> 4, r16 = lane & 15;

  f32x4 acc[MT][MT] = {};

  for (int k0 = 0; k0 < K; k0 += BK) {
    __syncthreads();
#pragma unroll
    for (int s = 0; s < NLOAD; ++s) {
      const int L = s * 256 + t;
      const int cj = L / BM, m = L % BM;
      const long ga = (long)(row0 + m) * lda + (k0 + cj * 8);
      const long gb = (long)(col0 + m) * ldb + (k0 + cj * 8);
      gload16(Ab0 + ga, AsH + L * 8);
      gload16(Bb0 + gb, BsH + L * 8);
      if (SPLIT) {
        gload16(Ab1 + ga, AsL + L * 8);
        gload16(Bb1 + gb, BsL + L * 8);
      }
    }
    __syncthreads();

#pragma unroll
    for (int kk = 0; kk < BK / 32; ++kk) {
      short8 a[MT], b[MT], al[MT], bl[MT];
#pragma unroll
      for (int mt = 0; mt < MT; ++mt) {
        const int o = (kk * 4 + jj) * BM * 8 + (wm + mt * 16 + r16) * 8;
        a[mt] = *(const short8*)(AsH + o);
        if (SPLIT) al[mt] = *(const short8*)(AsL + o);
      }
#pragma unroll
      for (int nt = 0; nt < MT; ++nt) {
        const int o = (kk * 4 + jj) * BM * 8 + (wn + nt * 16 + r16) * 8;
        b[nt] = *(const short8*)(BsH + o);
        if (SPLIT) bl[nt] = *(const short8*)(BsL + o);
      }
#pragma unroll
      for (int mt = 0; mt < MT; ++mt)
#pragma unroll
        for (int nt = 0; nt < MT; ++nt) {
          acc[mt][nt] = __builtin_amdgcn_mfma_f32_16x16x32_bf16(a[mt], b[nt], acc[mt][nt], 0, 0, 0);
          if (SPLIT) {
            acc[mt][nt] = __builtin_amdgcn_mfma_f32_16x16x32_bf16(a[mt], bl[nt], acc[mt][nt], 0, 0, 0);
            acc[mt][nt] = __builtin_amdgcn_mfma_f32_16x16x32_bf16(al[mt], b[nt], acc[mt][nt], 0, 0, 0);
          }
        }
    }
  }

#pragma unroll
  for (int mt = 0; mt < MT; ++mt)
#pragma unroll
    for (int nt = 0; nt < MT; ++nt)
#pragma unroll
      for (int r = 0; r < 4; ++r) {
        const int row = row0 + wm + mt * 16 + jj * 4 + r;
        const int col = col0 + wn + nt * 16 + r16;
        const float v = acc[mt][nt][r];
        if (MODE == 3) {
          const long i = bz * bsC + (long)row * 512 + col;
          const bf16 h = f2b(v);
          Whi[i] = h;
          Wlo[i] = f2b(v - b2f(h));
        } else if (MODE == 4) {
          const long i = bz * bsC + (long)row * 512 + col;
          const float nv = alpha * Xf[i] + beta * v;
          Xf[i] = nv;
          const bf16 h = f2b(nv);
          const bf16 l = f2b(nv - b2f(h));
          Whi[i] = h; Wlo[i] = l;
          const long it2 = bz * bsC + (long)col * 512 + row;
          Thi[it2] = h; Tlo[it2] = l;
        }
      }
}

// ---------------------------------------------------------------------------
// 256xBN pipelined NT GEMM, 8 waves (2x4), one barrier per phase (R4-verified).
// BN=256: deep prefetch, vmcnt(8) counted gates.  BN=128: 3-buffer rotation.
// MODE 0: bf16 store  MODE 1: GELU bf16  MODE 2: fp32 resf+acc
// ---------------------------------------------------------------------------
DEVINL void loadA4(const bf16* p, short8 (&dst)[4][2]) {
#pragma unroll
  for (int mf = 0; mf < 4; ++mf)
#pragma unroll
    for (int kk = 0; kk < 2; ++kk)
      dst[mf][kk] = *(const short8*)(p + kk * 4096 + mf * 128);
}
DEVINL void loadB2(const bf16* p, short8 (&dst)[2][2]) {
#pragma unroll
  for (int nf = 0; nf < 2; ++nf)
#pragma unroll
    for (int kk = 0; kk < 2; ++kk)
      dst[nf][kk] = *(const short8*)(p + kk * 4096 + nf * 128);
}
template <int QM, int QN>
DEVINL void mfma16(const short8 (&af)[4][2], const short8 (&bb)[2][2],
                   f32x4 (&acc)[8][4]) {
  __builtin_amdgcn_s_setprio(1);
#pragma unroll
  for (int mf = 0; mf < 4; ++mf)
#pragma unroll
    for (int nf = 0; nf < 2; ++nf)
#pragma unroll
      for (int kk = 0; kk < 2; ++kk)
        acc[QM * 4 + mf][QN * 2 + nf] = __builtin_amdgcn_mfma_f32_16x16x32_bf16(
            af[mf][kk], bb[nf][kk], acc[QM * 4 + mf][QN * 2 + nf], 0, 0, 0);
  __builtin_amdgcn_s_setprio(0);
}
template <int QM>
DEVINL void mfma16h(const short8 (&af)[4][2], const short8 (&bb)[2][2],
                    f32x4 (&acc)[8][2]) {
  __builtin_amdgcn_s_setprio(1);
#pragma unroll
  for (int mf = 0; mf < 4; ++mf)
#pragma unroll
    for (int nf = 0; nf < 2; ++nf)
#pragma unroll
      for (int kk = 0; kk < 2; ++kk)
        acc[QM * 4 + mf][nf] = __builtin_amdgcn_mfma_f32_16x16x32_bf16(
            af[mf][kk], bb[nf][kk], acc[QM * 4 + mf][nf], 0, 0, 0);
  __builtin_amdgcn_s_setprio(0);
}

template <int MODE, int BN>
__global__ __launch_bounds__(512, 2) void gemm256(
    const bf16* __restrict__ A, const bf16* __restrict__ B, int K, int lda,
    int ldb, bf16* __restrict__ outb, int ldo, const float* __restrict__ resf,
    float* __restrict__ outf) {
  extern __shared__ char smem[];
  const int t = threadIdx.x;
  const int lane = t & 63;
  const int w = t >> 6, wr = w >> 2, wc = w & 3;
  const int jj = lane >> 4, r16 = lane & 15;
  const int sm = t & 127, cj = t >> 7;

  const int row0 = blockIdx.x * 256;
  const int col0 = blockIdx.y * BN;

  const int aBase = (jj * 128 + wr * 64 + r16) * 8;
  const int bBase = (jj * 128 + wc * 32 + r16) * 8;

  if constexpr (BN == 256) {
    auto slotp = [&](int buf, int mat, int half) -> bf16* {
      return (bf16*)(smem + (((buf << 2) | (mat << 1) | half) << 14));
    };
    auto stageA = [&](int buf, int half, int kt) {
      bf16* dst = slotp(buf, 0, half) + t * 8;
      const long ga = (long)(row0 + half * 128 + sm) * lda + kt * 64 + cj * 8;
      gload16(A + ga, dst);
      gload16(A + ga + 32, dst + 4096);
    };
    auto stageB = [&](int buf, int half, int kt) {
      bf16* dst = slotp(buf, 1, half) + t * 8;
      const long gb = (long)(col0 + half * 128 + sm) * ldb + kt * 64 + cj * 8;
      gload16(B + gb, dst);
      gload16(B + gb + 32, dst + 4096);
    };

    f32x4 acc[8][4] = {};
    const int nit = K >> 7;

    stageA(0, 0, 0); stageB(0, 0, 0);
    stageB(0, 1, 0);
    stageA(0, 1, 0);
    stageA(1, 0, 1); stageB(1, 0, 1);
    stageB(1, 1, 1);
    WAIT_VM(8);
    BARRIER();

    for (int it = 0; it < nit; ++it) {
      const int k1 = 2 * it + 1, k2 = 2 * it + 2, k3 = 2 * it + 3;
      const bool more = (it + 1 < nit);
      short8 af[4][2], b0[2][2], b1[2][2];
      loadA4(slotp(0, 0, 0) + aBase, af);
      loadB2(slotp(0, 1, 0) + bBase, b0);
      stageA(1, 1, k1);
      BARRIER(); WAIT_LGKM0();
      mfma16<0, 0>(af, b0, acc);
      loadB2(slotp(0, 1, 1) + bBase, b1);
      WAIT_VM(8);
      BARRIER(); WAIT_LGKM0();
      mfma16<0, 1>(af, b1, acc);
      loadA4(slotp(0, 0, 1) + aBase, af);
      if (more) { stageA(0, 0, k2); stageB(0, 0, k2); }
      BARRIER(); WAIT_LGKM0();
      mfma16<1, 1>(af, b1, acc);
      if (more) { stageB(0, 1, k2); WAIT_VM(8); } else { WAIT_VM(0); }
      BARRIER();
      mfma16<1, 0>(af, b0, acc);
      loadA4(slotp(1, 0, 0) + aBase, af);
      loadB2(slotp(1, 1, 0) + bBase, b0);
      if (more) stageA(0, 1, k2);
      BARRIER(); WAIT_LGKM0();
      mfma16<0, 0>(af, b0, acc);
      loadB2(slotp(1, 1, 1) + bBase, b1);
      WAIT_VM(8);
      BARRIER(); WAIT_LGKM0();
      mfma16<0, 1>(af, b1, acc);
      loadA4(slotp(1, 0, 1) + aBase, af);
      if (more) { stageA(1, 0, k3); stageB(1, 0, k3); }
      BARRIER(); WAIT_LGKM0();
      mfma16<1, 1>(af, b1, acc);
      if (more) { stageB(1, 1, k3); WAIT_VM(8); }
      BARRIER();
      mfma16<1, 0>(af, b0, acc);
    }

    if constexpr (MODE == 2) {
#pragma unroll
      for (int q = 0; q < 8; ++q)
#pragma unroll
        for (int n = 0; n < 4; ++n)
#pragma unroll
          for (int r = 0; r < 4; ++r) {
            const int row = row0 + (q >> 2) * 128 + wr * 64 + (q & 3) * 16 + jj * 4 + r;
            const int col = col0 + (n >> 1) * 128 + wc * 32 + (n & 1) * 16 + r16;
            const long i = (long)row * ldo + col;
            outf[i] = resf[i] + acc[q][n][r];
          }
      return;
    } else {
      __syncthreads();
      bf16* Cs = (bf16*)smem;
#pragma unroll
      for (int q = 0; q < 8; ++q)
#pragma unroll
        for (int n = 0; n < 4; ++n)
#pragma unroll
          for (int r = 0; r < 4; ++r) {
            const int row = (q >> 2) * 128 + wr * 64 + (q & 3) * 16 + jj * 4 + r;
            const int col = (n >> 1) * 128 + wc * 32 + (n & 1) * 16 + r16;
            float v = acc[q][n][r];
            if (MODE == 1) v = gelu_exact(v);
            Cs[row * 256 + col] = f2b(v);
          }
      __syncthreads();
#pragma unroll
      for (int i = 0; i < 16; ++i) {
        const int rr = i * 16 + (t >> 5);
        const int cc = (t & 31) * 8;
        *(short8*)(outb + (long)(row0 + rr) * ldo + (col0 + cc)) =
            *(const short8*)(Cs + rr * 256 + cc);
      }
    }
  } else {
    // ---- BN == 128: 3-buffer rotation, 2 phases per K-tile, MODE 2 only ----
    auto slotp3 = [&](int buf, int slot) -> bf16* {
      return (bf16*)(smem + ((buf * 3 + slot) << 14));
    };
    auto stage3A = [&](int buf, int half, int kt) {
      bf16* dst = slotp3(buf, half) + t * 8;
      const long ga = (long)(row0 + half * 128 + sm) * lda + kt * 64 + cj * 8;
      gload16(A + ga, dst);
      gload16(A + ga + 32, dst + 4096);
    };
    auto stage3B = [&](int buf, int kt) {
      bf16* dst = slotp3(buf, 2) + t * 8;
      const long gb = (long)(col0 + sm) * ldb + kt * 64 + cj * 8;
      gload16(B + gb, dst);
      gload16(B + gb + 32, dst + 4096);
    };

    f32x4 acc[8][2] = {};
    const int nt = K >> 6;

    stage3A(0, 0, 0); stage3A(0, 1, 0); stage3B(0, 0);
    stage3A(1, 0, 1); stage3A(1, 1, 1); stage3B(1, 1);
    WAIT_VM(6);
    BARRIER();

    int cb = 0;
    for (int tk = 0; tk < nt; ++tk) {
      int sb = cb + 2; if (sb >= 3) sb -= 3;
      const bool more = (tk + 2 < nt);
      short8 af[4][2], bb2[2][2];
      bf16* sA0 = slotp3(cb, 0);
      bf16* sA1 = slotp3(cb, 1);
      bf16* sB = slotp3(cb, 2);
      loadA4(sA0 + aBase, af);
      loadB2(sB + bBase, bb2);
      BARRIER(); WAIT_LGKM0();
      mfma16h<0>(af, bb2, acc);
      loadA4(sA1 + aBase, af);
      if (more) {
        stage3A(sb, 0, tk + 2); stage3A(sb, 1, tk + 2); stage3B(sb, tk + 2);
        WAIT_VM(6);
      } else {
        WAIT_VM(0);
      }
      BARRIER(); WAIT_LGKM0();
      mfma16h<1>(af, bb2, acc);
      cb = (cb + 1 == 3) ? 0 : cb + 1;
    }

#pragma unroll
    for (int q = 0; q < 8; ++q)
#pragma unroll
      for (int n = 0; n < 2; ++n)
#pragma unroll
        for (int r = 0; r < 4; ++r) {
          const int row = row0 + (q >> 2) * 128 + wr * 64 + (q & 3) * 16 + jj * 4 + r;
          const int col = col0 + wc * 32 + n * 16 + r16;
          const long i = (long)row * ldo + col;
          outf[i] = resf[i] + acc[q][n][r];
        }
  }
}

// ---------------------------------------------------------------------------
// Fused pscan level: q'[t] = rmsnorm( q[t-d] @ P1^T + q[t] @ P2^T ) for
// t-batch0 >= d, else q'[t] = q[t]  (ping-pong Qsrc -> Qdst, race-free).
// Tile 64 rows x 512 cols (full row per block -> rmsnorm block-local).
// 512 threads = 8 waves (2x4), wave = 32 rows x 128 cols, acc[2][8].
// K=1024 concat: kt<8 reads q[t-d] (clamped), kt>=8 reads q[t]; B = Pcat.
// LDS 144 KiB: As[2] 8KB + Bs[2] 64KB double-buffered; ONE barrier per
// K-step: {stage kt+1 -> buf^1 | ds_read buf | MFMA | vm(0) lgkm(0) barrier}.
// Safety: my reads of buf complete (lgkm0) before I signal the barrier; DMA
// into buf issues only after ALL waves passed it. DMA into buf^1 drained
// (vm0) before barrier -> visible to next step's readers.
// Blocks fully below d copy rows and skip the GEMM.
// ---------------------------------------------------------------------------
__global__ __launch_bounds__(512, 1) void pscan_fused(
    const bf16* __restrict__ Qsrc, int ldq, bf16* __restrict__ Qdst,
    const bf16* __restrict__ Pcat, int d) {
  extern __shared__ char smem[];
  __shared__ float sums[64][4];
  const int t = threadIdx.x;
  const int lane = t & 63;
  const int w = t >> 6, wr = w >> 2, wc = w & 3;
  const int jj = lane >> 4, r16 = lane & 15;

  const int b = blockIdx.x >> 6;
  const int ty = blockIdx.x & 63;
  const int batch0 = b * 4096;
  const int row0 = batch0 + ty * 64;

  auto Asp = [&](int buf) -> bf16* { return (bf16*)smem + buf * 4096; };
  auto Bsp = [&](int buf) -> bf16* { return (bf16*)(smem + 16384) + buf * 32768; };

  bf16* Cs = (bf16*)smem;  // [64][512] epilogue staging (reuses As/Bs)

  if (row0 - batch0 + 63 >= d) {  // at least one row gets the GEMM result
    const int am = t & 63, acj = t >> 6;
    auto stage = [&](int kt, int buf) {
      {  // A: 8 KB, one 16B load/thread
        long ga;
        const int rr = row0 + am;
        if (kt < 8) {
          int rs = rr - d;
          if (rs < batch0) rs = batch0;  // garbage row, discarded by predicate
          ga = (long)rs * ldq + kt * 64 + acj * 8;
        } else {
          ga = (long)rr * ldq + (kt - 8) * 64 + acj * 8;
        }
        gload16(Qsrc + ga, Asp(buf) + t * 8);
      }
      bf16* bs = Bsp(buf);  // B: 64 KB, 8 loads/thread
#pragma unroll
      for (int s = 0; s < 8; ++s)
        gload16(Pcat + (long)t * 1024 + kt * 64 + s * 8, bs + (s * 512 + t) * 8);
    };

    f32x4 acc[2][8] = {};
    stage(0, 0);
    WAIT_VM(0);
    BARRIER();

    int cur = 0;
    for (int kt = 0; kt < 16; ++kt) {
      if (kt < 15) stage(kt + 1, cur ^ 1);
      const bf16* as = Asp(cur);
      const bf16* bs = Bsp(cur);
#pragma unroll
      for (int kk = 0; kk < 2; ++kk) {
        short8 a[2], bb[8];
#pragma unroll
        for (int mt = 0; mt < 2; ++mt)
          a[mt] = *(const short8*)(as + ((kk * 4 + jj) * 64 + wr * 32 + mt * 16 + r16) * 8);
#pragma unroll
        for (int nt = 0; nt < 8; ++nt)
          bb[nt] = *(const short8*)(bs + ((kk * 4 + jj) * 512 + wc * 128 + nt * 16 + r16) * 8);
#pragma unroll
        for (int mt = 0; mt < 2; ++mt)
#pragma unroll
          for (int nt = 0; nt < 8; ++nt)
            acc[mt][nt] = __builtin_amdgcn_mfma_f32_16x16x32_bf16(
                a[mt], bb[nt], acc[mt][nt], 0, 0, 0);
      }
      if (kt < 15) WAIT_VM(0);
      WAIT_LGKM0();   // my ds_reads of `cur` complete before I signal
      BARRIER();
      cur ^= 1;
    }

    // ---- fused rmsnorm over fp32 acc (cols of a row span r16 x nt x wc) ----
    float part[2][4];
#pragma unroll
    for (int mt = 0; mt < 2; ++mt)
#pragma unroll
      for (int r = 0; r < 4; ++r) {
        float s = 0.f;
#pragma unroll
        for (int nt = 0; nt < 8; ++nt) {
          const float v = acc[mt][nt][r];
          s += v * v;
        }
        part[mt][r] = s;
      }
#pragma unroll
    for (int off = 1; off < 16; off <<= 1)
#pragma unroll
      for (int mt = 0; mt < 2; ++mt)
#pragma unroll
        for (int r = 0; r < 4; ++r)
          part[mt][r] += __shfl_xor(part[mt][r], off, 64);
    if (r16 == 0) {
#pragma unroll
      for (int mt = 0; mt < 2; ++mt)
#pragma unroll
        for (int r = 0; r < 4; ++r)
          sums[wr * 32 + mt * 16 + jj * 4 + r][wc] = part[mt][r];
    }
    __syncthreads();
#pragma unroll
    for (int mt = 0; mt < 2; ++mt)
#pragma unroll
      for (int r = 0; r < 4; ++r) {
        const int rl = wr * 32 + mt * 16 + jj * 4 + r;
        const float tot = sums[rl][0] + sums[rl][1] + sums[rl][2] + sums[rl][3];
        const float inv = rsqrtf(tot * (1.0f / 512.0f) + 1e-6f);
#pragma unroll
        for (int nt = 0; nt < 8; ++nt)
          Cs[rl * 512 + wc * 128 + nt * 16 + r16] = f2b(acc[mt][nt][r] * inv);
      }
    __syncthreads();
  }

  // ---- write-out: rmsnorm result for t-batch0 >= d, else carry old q ----
#pragma unroll
  for (int s = 0; s < 8; ++s) {
    const int j = s * 512 + t;
    const int rl = j >> 6, c8 = (j & 63) * 8;
    const int trel = row0 + rl - batch0;
    short8 v8;
    if (trel >= d)
      v8 = *(const short8*)(Cs + rl * 512 + c8);
    else
      v8 = *(const short8*)(Qsrc + (long)(row0 + rl) * ldq + c8);
    *(short8*)(Qdst + (long)(row0 + rl) * 512 + c8) = v8;
  }
}

// Pcat[c][k] = k<512 ? P1[c][k] : P2[c][k-512]; P1=Xhi[0..], P2=Xhi[262144..].
__global__ __launch_bounds__(256) void repack_pcat(const bf16* __restrict__ Xhi,
                                                   bf16* __restrict__ Pcat) {
  const int e = (blockIdx.x * 256 + threadIdx.x) << 3;
  const int c = e >> 10, k = e & 1023;
  const bf16* src = (k < 512) ? (Xhi + (long)c * 512 + k)
                              : (Xhi + 262144 + (long)c * 512 + (k - 512));
  *(short8*)(Pcat + e) = *(const short8*)src;
}

// Frobenius norm^2 of W1, W2 (512x512 each).
__global__ __launch_bounds__(256) void fnorm(const float* __restrict__ W1,
                                             const float* __restrict__ W2,
                                             float* __restrict__ sigsq) {
  const int b = blockIdx.x >> 8;
  const float4 v = *(const float4*)((b ? W2 : W1) +
                                    (((long)(blockIdx.x & 255) * 256 + threadIdx.x) << 2));
  float s = v.x * v.x + v.y * v.y + v.z * v.z + v.w * v.w;
  s = wave_sum(s);
  if ((threadIdx.x & 63) == 0) atomicAdd(&sigsq[b], s);
}

// X0 = W / ||W||_F; emit fp32 master + hi/lo splits + transposed splits.
__global__ __launch_bounds__(256) void scale_init(
    const float* __restrict__ W1, const float* __restrict__ W2,
    const float* __restrict__ sigsq, float* __restrict__ Xf,
    bf16* __restrict__ Xhi, bf16* __restrict__ Xlo,
    bf16* __restrict__ Thi, bf16* __restrict__ Tlo) {
  const long idx = (long)blockIdx.x * 256 + threadIdx.x;
  const int b = (int)(idx >> 18);
  const int i = (int)(idx & 262143);
  const float s = rsqrtf(sigsq[b]);
  const float val = (b ? W2[i] : W1[i]) * s;
  const long o = ((long)b << 18) + i;
  Xf[o] = val;
  const bf16 h = f2b(val);
  const bf16 l = f2b(val - b2f(h));
  Xhi[o] = h; Xlo[o] = l;
  const int r = i >> 9, c = i & 511;
  const long ot = ((long)b << 18) + (long)c * 512 + r;
  Thi[ot] = h; Tlo[ot] = l;
}

// All five weight matrices fp32 -> bf16 in one launch (4 elems/thread).
__global__ __launch_bounds__(256) void convert_weights(
    const float* __restrict__ Wq, const float* __restrict__ Wv,
    const float* __restrict__ Wo, const float* __restrict__ Wfc,
    const float* __restrict__ Wpr, bf16* __restrict__ Wqvb,
    bf16* __restrict__ Wob, bf16* __restrict__ Wfcb, bf16* __restrict__ Wprb) {
  const long e = ((long)blockIdx.x * 256 + threadIdx.x) << 2;
  const float* src; bf16* dst; long off;
  if (e < 262144)       { src = Wq;  dst = Wqvb;          off = e; }
  else if (e < 524288)  { src = Wv;  dst = Wqvb + 262144; off = e - 262144; }
  else if (e < 786432)  { src = Wo;  dst = Wob;           off = e - 524288; }
  else if (e < 1835008) { src = Wfc; dst = Wfcb;          off = e - 786432; }
  else                  { src = Wpr; dst = Wprb;          off = e - 1835008; }
  const float4 v = *(const float4*)(src + off);
  short4v o4;
  o4[0] = f2sb(v.x); o4[1] = f2sb(v.y); o4[2] = f2sb(v.z); o4[3] = f2sb(v.w);
  *(short4v*)(dst + off) = o4;
}

// LayerNorm over C=512, one wave per row (4 rows/block), bf16 out.
__global__ __launch_bounds__(256) void ln_rows(const float* __restrict__ x,
                                               const float* __restrict__ w,
                                               bf16* __restrict__ out) {
  const int row = (blockIdx.x << 2) + (threadIdx.x >> 6);
  const int lane = threadIdx.x & 63;
  const float* xr = x + (long)row * 512 + lane * 8;
  const float4 a = *(const float4*)xr;
  const float4 b = *(const float4*)(xr + 4);
  float v[8] = {a.x, a.y, a.z, a.w, b.x, b.y, b.z, b.w};
  float s1 = 0.f, s2 = 0.f;
#pragma unroll
  for (int i = 0; i < 8; ++i) { s1 += v[i]; s2 += v[i] * v[i]; }
  s1 = wave_allsum(s1);
  s2 = wave_allsum(s2);
  const float mean = s1 * (1.0f / 512.0f);
  const float var = s2 * (1.0f / 512.0f) - mean * mean;
  const float inv = rsqrtf(var + 1e-5f);
  const float4 w1 = *(const float4*)(w + lane * 8);
  const float4 w2 = *(const float4*)(w + lane * 8 + 4);
  const float wv[8] = {w1.x, w1.y, w1.z, w1.w, w2.x, w2.y, w2.z, w2.w};
  short8 o8;
#pragma unroll
  for (int i = 0; i < 8; ++i) o8[i] = f2sb((v[i] - mean) * inv * wv[i]);
  *(short8*)(out + (long)row * 512 + lane * 8) = o8;
}

// u = q * v elementwise, 8 elems/thread. q standalone (ld 512), v in QV.
__global__ __launch_bounds__(256) void qv_mul(const bf16* __restrict__ Q,
                                              const bf16* __restrict__ QV,
                                              bf16* __restrict__ u) {
  const long base = ((long)blockIdx.x * 256 + threadIdx.x) << 3;
  const long row = base >> 9;
  const int c = (int)(base & 511);
  const short8 q8 = *(const short8*)(Q + row * 512 + c);
  const short8 v8 = *(const short8*)(QV + row * 1024 + 512 + c);
  short8 o8;
#pragma unroll
  for (int i = 0; i < 8; ++i) o8[i] = f2sb(sb2f(q8[i]) * sb2f(v8[i]));
  *(short8*)(u + row * 512 + c) = o8;
}

// ---------------------------------------------------------------------------
extern "C" void kernel_launch(void* const* d_in, const int* in_sizes, int n_in,
                              void* d_out, int out_size, void* d_ws, size_t ws_size,
                              hipStream_t stream) {
  (void)in_sizes; (void)n_in; (void)out_size; (void)ws_size;
  const float* x    = (const float*)d_in[0];
  const float* ln1w = (const float*)d_in[1];
  const float* Wq   = (const float*)d_in[2];
  const float* Wv   = (const float*)d_in[3];
  const float* Wo   = (const float*)d_in[4];
  // d_in[5] = identity: provably unused (positions t<d are never updated)
  const float* Wp1  = (const float*)d_in[6];
  const float* Wp2  = (const float*)d_in[7];
  const float* ln2w = (const float*)d_in[8];
  const float* Wfc  = (const float*)d_in[9];
  const float* Wpr  = (const float*)d_in[10];
  float* out = (float*)d_out;

  const long M = 16384;
  char* ws = (char*)d_ws;
  size_t off = 0;
  auto alloc = [&](size_t bytes) -> void* {
    void* p = ws + off;
    off += (bytes + 255) & ~(size_t)255;
    return p;
  };
  bf16* YZ   = (bf16*)alloc(M * 1024 * 2);   // Qa|Qb ping-pong; later h3 low half
  bf16* QV   = (bf16*)alloc(M * 1024 * 2);   // 32MB [q|v]
  bf16* hb   = (bf16*)alloc(M * 512 * 2);    // h -> u -> h2
  bf16* Wqvb = (bf16*)alloc(1024 * 512 * 2);
  bf16* Wob  = (bf16*)alloc(512 * 512 * 2);
  bf16* Wfcb = (bf16*)alloc(2048 * 512 * 2);
  bf16* Wprb = (bf16*)alloc(512 * 2048 * 2);
  float* Xf  = (float*)alloc(2 * 262144 * 4);
  bf16* Xhi  = (bf16*)alloc(2 * 262144 * 2);  // final [P1;P2] bf16 (1024x512)
  bf16* Xlo  = (bf16*)alloc(2 * 262144 * 2);
  bf16* XtAh = (bf16*)alloc(2 * 262144 * 2);
  bf16* XtAl = (bf16*)alloc(2 * 262144 * 2);
  bf16* XtBh = (bf16*)alloc(2 * 262144 * 2);
  bf16* XtBl = (bf16*)alloc(2 * 262144 * 2);
  bf16* Ghi  = (bf16*)alloc(2 * 262144 * 2);
  bf16* Glo  = (bf16*)alloc(2 * 262144 * 2);
  bf16* Pcat = (bf16*)alloc(512 * 1024 * 2);  // [c][P1[c,:]|P2[c,:]]
  float* sig = (float*)alloc(256);
  bf16* Qa = YZ;              // [16384][512] bf16, 16MB
  bf16* Qb = YZ + 8388608;    // [16384][512] bf16, 16MB
  bf16* h3 = YZ;              // [16384,2048] bf16 spans YZ+QV (both dead by then)

  const auto Z0 = nullptr;

  // --- polar decomposition of Wp1, Wp2 (batched Newton-Schulz, split-bf16 MFMA)
  hipMemsetAsync(sig, 0, 2 * sizeof(float), stream);
  fnorm<<<512, 256, 0, stream>>>(Wp1, Wp2, sig);
  scale_init<<<2048, 256, 0, stream>>>(Wp1, Wp2, sig, Xf, Xhi, Xlo, XtAh, XtAl);

  bf16 *tch = XtAh, *tcl = XtAl, *tnh = XtBh, *tnl = XtBl;
  const long Sz = 262144;
  for (int i = 0; i < 20; ++i) {
    const bool pol = (i >= 16);          // 16 doublings + 4 polish
    const float ac = pol ? 1.5f : 2.0f;
    const float bc = pol ? -0.5f : -1.0f;
    dim3 g(8, 8, 2);
    gemm_nt<3, true, 64><<<g, 256, 32768, stream>>>(
        Xhi, Xlo, Xhi, Xlo, 512, 512, 512, Sz, Sz, Sz,
        0.f, 0.f, Z0, Ghi, Glo, Z0, Z0);
    gemm_nt<4, true, 64><<<g, 256, 32768, stream>>>(
        Ghi, Glo, tch, tcl, 512, 512, 512, Sz, Sz, Sz,
        ac, bc, Xf, Xhi, Xlo, tnh, tnl);
    bf16* sw;
    sw = tch; tch = tnh; tnh = sw;
    sw = tcl; tcl = tnl; tnl = sw;
  }
  repack_pcat<<<256, 256, 0, stream>>>(Xhi, Pcat);

  // --- weight conversions to bf16 (one launch)
  convert_weights<<<2816, 256, 0, stream>>>(Wq, Wv, Wo, Wfc, Wpr, Wqvb, Wob, Wfcb, Wprb);

  // --- SSM branch
  ln_rows<<<4096, 256, 0, stream>>>(x, ln1w, hb);
  // [q|v] = h @ [Wq;Wv]^T   (M=16384, N=1024, K=512)
  gemm256<0, 256><<<dim3(64, 4), 512, 131072, stream>>>(
      hb, Wqvb, 512, 512, 512, QV, 1024, Z0, Z0);

  // --- pscan: fused GEMM+rmsnorm per level, ping-pong q
  {
    const bf16* qsrc = QV;  // q half of QV, ld 1024
    int ldq = 1024;
    bf16* qdst = Qa;
    for (int d = 1; d < 4096; d <<= 1) {
      pscan_fused<<<256, 512, 147456, stream>>>(qsrc, ldq, qdst, Pcat, d);
      qsrc = qdst;
      ldq = 512;
      qdst = (qdst == Qa) ? Qb : Qa;
    }
    qv_mul<<<4096, 256, 0, stream>>>(qsrc, QV, hb);  // u -> hb
  }

  // x2 = x + u @ Wo^T  -> d_out (fp32)  (N=512 -> BN=128 grid (64,4))
  gemm256<2, 128><<<dim3(64, 4), 512, 147456, stream>>>(
      hb, Wob, 512, 512, 512, Z0, 512, x, out);

  // --- MLP branch
  ln_rows<<<4096, 256, 0, stream>>>(out, ln2w, hb);  // h2 -> hb
  gemm256<1, 256><<<dim3(64, 8), 512, 131072, stream>>>(
      hb, Wfcb, 512, 512, 512, h3, 2048, Z0, Z0);
  gemm256<2, 128><<<dim3(64, 4), 512, 147456, stream>>>(
      h3, Wprb, 2048, 2048, 2048, Z0, 512, out, out);
}

// Round 7
// 1293.514 us; speedup vs baseline: 1.2885x; 1.2885x over previous
//
#include <hip/hip_runtime.h>
#include <hip/hip_bf16.h>

typedef __hip_bfloat16 bf16;
typedef __attribute__((ext_vector_type(8))) short short8;
typedef __attribute__((ext_vector_type(4))) short short4v;
typedef __attribute__((ext_vector_type(4))) float f32x4;

#define DEVINL static __device__ __forceinline__

DEVINL float b2f(bf16 x) { return __bfloat162float(x); }
DEVINL bf16 f2b(float x) { return __float2bfloat16(x); }
DEVINL float sb2f(short s) { return b2f(__builtin_bit_cast(bf16, s)); }
DEVINL short f2sb(float x) { return __builtin_bit_cast(short, f2b(x)); }

DEVINL void gload16(const void* g, void* l) {
  __builtin_amdgcn_global_load_lds(
      (const __attribute__((address_space(1))) void*)g,
      (__attribute__((address_space(3))) void*)l, 16, 0, 0);
}

DEVINL float wave_sum(float v) {
#pragma unroll
  for (int o = 32; o > 0; o >>= 1) v += __shfl_down(v, o, 64);
  return v;
}

DEVINL float wave_allsum(float v) {
#pragma unroll
  for (int o = 32; o > 0; o >>= 1) v += __shfl_xor(v, o, 64);
  return v;
}

// Exact-erf GELU via Abramowitz-Stegun 7.1.26 (max abs err 1.5e-7 in erf,
// far below bf16 output rounding).
DEVINL float gelu_exact(float v) {
  const float z = v * 0.70710678118654752f;
  const float az = fabsf(z);
  const float t = 1.0f / (1.0f + 0.3275911f * az);
  float p = 1.061405429f;
  p = p * t - 1.453152027f;
  p = p * t + 1.421413741f;
  p = p * t - 0.284496736f;
  p = p * t + 0.254829592f;
  const float e = __expf(-z * z);
  const float erf_az = 1.0f - p * t * e;
  const float er = (z < 0.f) ? -erf_az : erf_az;
  return 0.5f * v * (1.0f + er);
}

#define BARRIER()                             \
  do {                                        \
    __asm__ __volatile__("" ::: "memory");    \
    __builtin_amdgcn_s_barrier();             \
    __asm__ __volatile__("" ::: "memory");    \
  } while (0)
#define WAIT_LGKM0() __asm__ __volatile__("s_waitcnt lgkmcnt(0)" ::: "memory")
#define WAIT_VM(n) __asm__ __volatile__("s_waitcnt vmcnt(" #n ")" ::: "memory")

// ---------------------------------------------------------------------------
// Newton-Schulz small GEMM (512x512x512, split hi/lo bf16), 3-buffer
// pipelined: 64x64 tile, BK=64, 8 K-tiles, 256 threads (4 waves 2x2).
// Pipeline: tile tk+2 staged (8 gload16/thread) during tile tk's compute;
// counted WAIT_VM(8) gate before the barrier ending PhB (waits tile tk+1's
// 8 loads; invariant: exactly 8 outstanding after each gate). Slot reuse is
// 2-barrier separated (same audit as the BN=128 path): tile tk-1's last
// ds_reads are lgkm0-drained by every wave before PhA(tk)'s barrier, and
// the DMA into that slot issues only after it. MFMA order identical to the
// legacy kernel -> bit-identical numerics.
// MODE 3: G = X@X^T, split-write hi/lo.  MODE 4: X' = alpha*Xf + beta*acc,
// write fp32 master + hi/lo + transposed hi/lo.
// ---------------------------------------------------------------------------
template <int MODE>
__global__ __launch_bounds__(256) void gemm_ns(
    const bf16* __restrict__ A0, const bf16* __restrict__ A1,
    const bf16* __restrict__ B0, const bf16* __restrict__ B1,
    long bsA, long bsB, long bsC,
    float alpha, float beta, float* __restrict__ Xf,
    bf16* __restrict__ Whi, bf16* __restrict__ Wlo,
    bf16* __restrict__ Thi, bf16* __restrict__ Tlo) {
  extern __shared__ char smem[];  // 3 x 32KB
  const int t = threadIdx.x;
  const int lane = t & 63, w = t >> 6;
  const long bz = blockIdx.z;
  const bf16* Ab0 = A0 + bz * bsA;
  const bf16* Bb0 = B0 + bz * bsB;
  const bf16* Ab1 = A1 + bz * bsA;
  const bf16* Bb1 = B1 + bz * bsB;
  const int row0 = blockIdx.x * 64, col0 = blockIdx.y * 64;
  const int wm = (w >> 1) * 32, wn = (w & 1) * 32;
  const int jj = lane >> 4, r16 = lane & 15;

  auto buf = [&](int b, int arr) -> bf16* {  // 0=AsH 1=BsH 2=AsL 3=BsL
    return (bf16*)(smem + b * 32768 + arr * 8192);
  };
  auto stage = [&](int bi, int kt) {
#pragma unroll
    for (int s = 0; s < 2; ++s) {
      const int L = s * 256 + t;
      const int cj = L >> 6, m = L & 63;
      const long ga = (long)(row0 + m) * 512 + kt * 64 + cj * 8;
      const long gb = (long)(col0 + m) * 512 + kt * 64 + cj * 8;
      gload16(Ab0 + ga, buf(bi, 0) + L * 8);
      gload16(Bb0 + gb, buf(bi, 1) + L * 8);
      gload16(Ab1 + ga, buf(bi, 2) + L * 8);
      gload16(Bb1 + gb, buf(bi, 3) + L * 8);
    }
  };

  f32x4 acc[2][2] = {};

  stage(0, 0); stage(1, 1);
  WAIT_VM(8);
  BARRIER();

  for (int tk = 0; tk < 8; ++tk) {
    const int cb = tk % 3;
    const int sb = (tk + 2) % 3;
    bf16* ah = buf(cb, 0); bf16* bh = buf(cb, 1);
    bf16* alp = buf(cb, 2); bf16* blp = buf(cb, 3);
    short8 a[2], b[2], al[2], bl[2];
    // ---- PhA: kk=0 ----
#pragma unroll
    for (int mt = 0; mt < 2; ++mt) {
      const int o = (jj * 64 + wm + mt * 16 + r16) * 8;
      a[mt] = *(const short8*)(ah + o);
      al[mt] = *(const short8*)(alp + o);
    }
#pragma unroll
    for (int nt = 0; nt < 2; ++nt) {
      const int o = (jj * 64 + wn + nt * 16 + r16) * 8;
      b[nt] = *(const short8*)(bh + o);
      bl[nt] = *(const short8*)(blp + o);
    }
    BARRIER(); WAIT_LGKM0();
#pragma unroll
    for (int mt = 0; mt < 2; ++mt)
#pragma unroll
      for (int nt = 0; nt < 2; ++nt) {
        acc[mt][nt] = __builtin_amdgcn_mfma_f32_16x16x32_bf16(a[mt], b[nt], acc[mt][nt], 0, 0, 0);
        acc[mt][nt] = __builtin_amdgcn_mfma_f32_16x16x32_bf16(a[mt], bl[nt], acc[mt][nt], 0, 0, 0);
        acc[mt][nt] = __builtin_amdgcn_mfma_f32_16x16x32_bf16(al[mt], b[nt], acc[mt][nt], 0, 0, 0);
      }
    // ---- PhB: kk=1; stage tk+2; counted gate ----
#pragma unroll
    for (int mt = 0; mt < 2; ++mt) {
      const int o = ((4 + jj) * 64 + wm + mt * 16 + r16) * 8;
      a[mt] = *(const short8*)(ah + o);
      al[mt] = *(const short8*)(alp + o);
    }
#pragma unroll
    for (int nt = 0; nt < 2; ++nt) {
      const int o = ((4 + jj) * 64 + wn + nt * 16 + r16) * 8;
      b[nt] = *(const short8*)(bh + o);
      bl[nt] = *(const short8*)(blp + o);
    }
    if (tk + 2 < 8) {
      stage(sb, tk + 2);
      WAIT_VM(8);
    } else if (tk + 1 < 8) {
      WAIT_VM(0);
    }
    BARRIER(); WAIT_LGKM0();
#pragma unroll
    for (int mt = 0; mt < 2; ++mt)
#pragma unroll
      for (int nt = 0; nt < 2; ++nt) {
        acc[mt][nt] = __builtin_amdgcn_mfma_f32_16x16x32_bf16(a[mt], b[nt], acc[mt][nt], 0, 0, 0);
        acc[mt][nt] = __builtin_amdgcn_mfma_f32_16x16x32_bf16(a[mt], bl[nt], acc[mt][nt], 0, 0, 0);
        acc[mt][nt] = __builtin_amdgcn_mfma_f32_16x16x32_bf16(al[mt], b[nt], acc[mt][nt], 0, 0, 0);
      }
  }

#pragma unroll
  for (int mt = 0; mt < 2; ++mt)
#pragma unroll
    for (int nt = 0; nt < 2; ++nt)
#pragma unroll
      for (int r = 0; r < 4; ++r) {
        const int row = row0 + wm + mt * 16 + jj * 4 + r;
        const int col = col0 + wn + nt * 16 + r16;
        const float v = acc[mt][nt][r];
        if (MODE == 3) {
          const long i = bz * bsC + (long)row * 512 + col;
          const bf16 h = f2b(v);
          Whi[i] = h;
          Wlo[i] = f2b(v - b2f(h));
        } else {
          const long i = bz * bsC + (long)row * 512 + col;
          const float nv = alpha * Xf[i] + beta * v;
          Xf[i] = nv;
          const bf16 h = f2b(nv);
          const bf16 l = f2b(nv - b2f(h));
          Whi[i] = h; Wlo[i] = l;
          const long it2 = bz * bsC + (long)col * 512 + row;
          Thi[it2] = h; Tlo[it2] = l;
        }
      }
}

// ---------------------------------------------------------------------------
// 256xBN pipelined NT GEMM, 8 waves (2x4), one barrier per phase (R4-verified).
// BN=256: deep prefetch, vmcnt(8) counted gates.  BN=128: 3-buffer rotation.
// MODE 0: bf16 store  MODE 1: GELU bf16  MODE 2: fp32 resf+acc
// ---------------------------------------------------------------------------
DEVINL void loadA4(const bf16* p, short8 (&dst)[4][2]) {
#pragma unroll
  for (int mf = 0; mf < 4; ++mf)
#pragma unroll
    for (int kk = 0; kk < 2; ++kk)
      dst[mf][kk] = *(const short8*)(p + kk * 4096 + mf * 128);
}
DEVINL void loadB2(const bf16* p, short8 (&dst)[2][2]) {
#pragma unroll
  for (int nf = 0; nf < 2; ++nf)
#pragma unroll
    for (int kk = 0; kk < 2; ++kk)
      dst[nf][kk] = *(const short8*)(p + kk * 4096 + nf * 128);
}
template <int QM, int QN>
DEVINL void mfma16(const short8 (&af)[4][2], const short8 (&bb)[2][2],
                   f32x4 (&acc)[8][4]) {
  __builtin_amdgcn_s_setprio(1);
#pragma unroll
  for (int mf = 0; mf < 4; ++mf)
#pragma unroll
    for (int nf = 0; nf < 2; ++nf)
#pragma unroll
      for (int kk = 0; kk < 2; ++kk)
        acc[QM * 4 + mf][QN * 2 + nf] = __builtin_amdgcn_mfma_f32_16x16x32_bf16(
            af[mf][kk], bb[nf][kk], acc[QM * 4 + mf][QN * 2 + nf], 0, 0, 0);
  __builtin_amdgcn_s_setprio(0);
}
template <int QM>
DEVINL void mfma16h(const short8 (&af)[4][2], const short8 (&bb)[2][2],
                    f32x4 (&acc)[8][2]) {
  __builtin_amdgcn_s_setprio(1);
#pragma unroll
  for (int mf = 0; mf < 4; ++mf)
#pragma unroll
    for (int nf = 0; nf < 2; ++nf)
#pragma unroll
      for (int kk = 0; kk < 2; ++kk)
        acc[QM * 4 + mf][nf] = __builtin_amdgcn_mfma_f32_16x16x32_bf16(
            af[mf][kk], bb[nf][kk], acc[QM * 4 + mf][nf], 0, 0, 0);
  __builtin_amdgcn_s_setprio(0);
}

template <int MODE, int BN>
__global__ __launch_bounds__(512, 2) void gemm256(
    const bf16* __restrict__ A, const bf16* __restrict__ B, int K, int lda,
    int ldb, bf16* __restrict__ outb, int ldo, const float* __restrict__ resf,
    float* __restrict__ outf) {
  extern __shared__ char smem[];
  const int t = threadIdx.x;
  const int lane = t & 63;
  const int w = t >> 6, wr = w >> 2, wc = w & 3;
  const int jj = lane >> 4, r16 = lane & 15;
  const int sm = t & 127, cj = t >> 7;

  const int row0 = blockIdx.x * 256;
  const int col0 = blockIdx.y * BN;

  const int aBase = (jj * 128 + wr * 64 + r16) * 8;
  const int bBase = (jj * 128 + wc * 32 + r16) * 8;

  if constexpr (BN == 256) {
    auto slotp = [&](int buf, int mat, int half) -> bf16* {
      return (bf16*)(smem + (((buf << 2) | (mat << 1) | half) << 14));
    };
    auto stageA = [&](int buf, int half, int kt) {
      bf16* dst = slotp(buf, 0, half) + t * 8;
      const long ga = (long)(row0 + half * 128 + sm) * lda + kt * 64 + cj * 8;
      gload16(A + ga, dst);
      gload16(A + ga + 32, dst + 4096);
    };
    auto stageB = [&](int buf, int half, int kt) {
      bf16* dst = slotp(buf, 1, half) + t * 8;
      const long gb = (long)(col0 + half * 128 + sm) * ldb + kt * 64 + cj * 8;
      gload16(B + gb, dst);
      gload16(B + gb + 32, dst + 4096);
    };

    f32x4 acc[8][4] = {};
    const int nit = K >> 7;

    stageA(0, 0, 0); stageB(0, 0, 0);
    stageB(0, 1, 0);
    stageA(0, 1, 0);
    stageA(1, 0, 1); stageB(1, 0, 1);
    stageB(1, 1, 1);
    WAIT_VM(8);
    BARRIER();

    for (int it = 0; it < nit; ++it) {
      const int k1 = 2 * it + 1, k2 = 2 * it + 2, k3 = 2 * it + 3;
      const bool more = (it + 1 < nit);
      short8 af[4][2], b0[2][2], b1[2][2];
      loadA4(slotp(0, 0, 0) + aBase, af);
      loadB2(slotp(0, 1, 0) + bBase, b0);
      stageA(1, 1, k1);
      BARRIER(); WAIT_LGKM0();
      mfma16<0, 0>(af, b0, acc);
      loadB2(slotp(0, 1, 1) + bBase, b1);
      WAIT_VM(8);
      BARRIER(); WAIT_LGKM0();
      mfma16<0, 1>(af, b1, acc);
      loadA4(slotp(0, 0, 1) + aBase, af);
      if (more) { stageA(0, 0, k2); stageB(0, 0, k2); }
      BARRIER(); WAIT_LGKM0();
      mfma16<1, 1>(af, b1, acc);
      if (more) { stageB(0, 1, k2); WAIT_VM(8); } else { WAIT_VM(0); }
      BARRIER();
      mfma16<1, 0>(af, b0, acc);
      loadA4(slotp(1, 0, 0) + aBase, af);
      loadB2(slotp(1, 1, 0) + bBase, b0);
      if (more) stageA(0, 1, k2);
      BARRIER(); WAIT_LGKM0();
      mfma16<0, 0>(af, b0, acc);
      loadB2(slotp(1, 1, 1) + bBase, b1);
      WAIT_VM(8);
      BARRIER(); WAIT_LGKM0();
      mfma16<0, 1>(af, b1, acc);
      loadA4(slotp(1, 0, 1) + aBase, af);
      if (more) { stageA(1, 0, k3); stageB(1, 0, k3); }
      BARRIER(); WAIT_LGKM0();
      mfma16<1, 1>(af, b1, acc);
      if (more) { stageB(1, 1, k3); WAIT_VM(8); }
      BARRIER();
      mfma16<1, 0>(af, b0, acc);
    }

    if constexpr (MODE == 2) {
#pragma unroll
      for (int q = 0; q < 8; ++q)
#pragma unroll
        for (int n = 0; n < 4; ++n)
#pragma unroll
          for (int r = 0; r < 4; ++r) {
            const int row = row0 + (q >> 2) * 128 + wr * 64 + (q & 3) * 16 + jj * 4 + r;
            const int col = col0 + (n >> 1) * 128 + wc * 32 + (n & 1) * 16 + r16;
            const long i = (long)row * ldo + col;
            outf[i] = resf[i] + acc[q][n][r];
          }
      return;
    } else {
      __syncthreads();
      bf16* Cs = (bf16*)smem;
#pragma unroll
      for (int q = 0; q < 8; ++q)
#pragma unroll
        for (int n = 0; n < 4; ++n)
#pragma unroll
          for (int r = 0; r < 4; ++r) {
            const int row = (q >> 2) * 128 + wr * 64 + (q & 3) * 16 + jj * 4 + r;
            const int col = (n >> 1) * 128 + wc * 32 + (n & 1) * 16 + r16;
            float v = acc[q][n][r];
            if (MODE == 1) v = gelu_exact(v);
            Cs[row * 256 + col] = f2b(v);
          }
      __syncthreads();
#pragma unroll
      for (int i = 0; i < 16; ++i) {
        const int rr = i * 16 + (t >> 5);
        const int cc = (t & 31) * 8;
        *(short8*)(outb + (long)(row0 + rr) * ldo + (col0 + cc)) =
            *(const short8*)(Cs + rr * 256 + cc);
      }
    }
  } else {
    // ---- BN == 128: 3-buffer rotation, 2 phases per K-tile, MODE 2 only ----
    auto slotp3 = [&](int buf, int slot) -> bf16* {
      return (bf16*)(smem + ((buf * 3 + slot) << 14));
    };
    auto stage3A = [&](int buf, int half, int kt) {
      bf16* dst = slotp3(buf, half) + t * 8;
      const long ga = (long)(row0 + half * 128 + sm) * lda + kt * 64 + cj * 8;
      gload16(A + ga, dst);
      gload16(A + ga + 32, dst + 4096);
    };
    auto stage3B = [&](int buf, int kt) {
      bf16* dst = slotp3(buf, 2) + t * 8;
      const long gb = (long)(col0 + sm) * ldb + kt * 64 + cj * 8;
      gload16(B + gb, dst);
      gload16(B + gb + 32, dst + 4096);
    };

    f32x4 acc[8][2] = {};
    const int nt = K >> 6;

    stage3A(0, 0, 0); stage3A(0, 1, 0); stage3B(0, 0);
    stage3A(1, 0, 1); stage3A(1, 1, 1); stage3B(1, 1);
    WAIT_VM(6);
    BARRIER();

    int cb = 0;
    for (int tk = 0; tk < nt; ++tk) {
      int sb = cb + 2; if (sb >= 3) sb -= 3;
      const bool more = (tk + 2 < nt);
      short8 af[4][2], bb2[2][2];
      bf16* sA0 = slotp3(cb, 0);
      bf16* sA1 = slotp3(cb, 1);
      bf16* sB = slotp3(cb, 2);
      loadA4(sA0 + aBase, af);
      loadB2(sB + bBase, bb2);
      BARRIER(); WAIT_LGKM0();
      mfma16h<0>(af, bb2, acc);
      loadA4(sA1 + aBase, af);
      if (more) {
        stage3A(sb, 0, tk + 2); stage3A(sb, 1, tk + 2); stage3B(sb, tk + 2);
        WAIT_VM(6);
      } else {
        WAIT_VM(0);
      }
      BARRIER(); WAIT_LGKM0();
      mfma16h<1>(af, bb2, acc);
      cb = (cb + 1 == 3) ? 0 : cb + 1;
    }

#pragma unroll
    for (int q = 0; q < 8; ++q)
#pragma unroll
      for (int n = 0; n < 2; ++n)
#pragma unroll
        for (int r = 0; r < 4; ++r) {
          const int row = row0 + (q >> 2) * 128 + wr * 64 + (q & 3) * 16 + jj * 4 + r;
          const int col = col0 + wc * 32 + n * 16 + r16;
          const long i = (long)row * ldo + col;
          outf[i] = resf[i] + acc[q][n][r];
        }
  }
}

// Frobenius norm^2 of W1, W2 (512x512 each).
__global__ __launch_bounds__(256) void fnorm(const float* __restrict__ W1,
                                             const float* __restrict__ W2,
                                             float* __restrict__ sigsq) {
  const int b = blockIdx.x >> 8;
  const float4 v = *(const float4*)((b ? W2 : W1) +
                                    (((long)(blockIdx.x & 255) * 256 + threadIdx.x) << 2));
  float s = v.x * v.x + v.y * v.y + v.z * v.z + v.w * v.w;
  s = wave_sum(s);
  if ((threadIdx.x & 63) == 0) atomicAdd(&sigsq[b], s);
}

// X0 = W / ||W||_F; emit fp32 master + hi/lo splits + transposed splits.
__global__ __launch_bounds__(256) void scale_init(
    const float* __restrict__ W1, const float* __restrict__ W2,
    const float* __restrict__ sigsq, float* __restrict__ Xf,
    bf16* __restrict__ Xhi, bf16* __restrict__ Xlo,
    bf16* __restrict__ Thi, bf16* __restrict__ Tlo) {
  const long idx = (long)blockIdx.x * 256 + threadIdx.x;
  const int b = (int)(idx >> 18);
  const int i = (int)(idx & 262143);
  const float s = rsqrtf(sigsq[b]);
  const float val = (b ? W2[i] : W1[i]) * s;
  const long o = ((long)b << 18) + i;
  Xf[o] = val;
  const bf16 h = f2b(val);
  const bf16 l = f2b(val - b2f(h));
  Xhi[o] = h; Xlo[o] = l;
  const int r = i >> 9, c = i & 511;
  const long ot = ((long)b << 18) + (long)c * 512 + r;
  Thi[ot] = h; Tlo[ot] = l;
}

// All five weight matrices fp32 -> bf16 in one launch (4 elems/thread).
__global__ __launch_bounds__(256) void convert_weights(
    const float* __restrict__ Wq, const float* __restrict__ Wv,
    const float* __restrict__ Wo, const float* __restrict__ Wfc,
    const float* __restrict__ Wpr, bf16* __restrict__ Wqvb,
    bf16* __restrict__ Wob, bf16* __restrict__ Wfcb, bf16* __restrict__ Wprb) {
  const long e = ((long)blockIdx.x * 256 + threadIdx.x) << 2;
  const float* src; bf16* dst; long off;
  if (e < 262144)       { src = Wq;  dst = Wqvb;          off = e; }
  else if (e < 524288)  { src = Wv;  dst = Wqvb + 262144; off = e - 262144; }
  else if (e < 786432)  { src = Wo;  dst = Wob;           off = e - 524288; }
  else if (e < 1835008) { src = Wfc; dst = Wfcb;          off = e - 786432; }
  else                  { src = Wpr; dst = Wprb;          off = e - 1835008; }
  const float4 v = *(const float4*)(src + off);
  short4v o4;
  o4[0] = f2sb(v.x); o4[1] = f2sb(v.y); o4[2] = f2sb(v.z); o4[3] = f2sb(v.w);
  *(short4v*)(dst + off) = o4;
}

// LayerNorm over C=512, one wave per row (4 rows/block), bf16 out.
__global__ __launch_bounds__(256) void ln_rows(const float* __restrict__ x,
                                               const float* __restrict__ w,
                                               bf16* __restrict__ out) {
  const int row = (blockIdx.x << 2) + (threadIdx.x >> 6);
  const int lane = threadIdx.x & 63;
  const float* xr = x + (long)row * 512 + lane * 8;
  const float4 a = *(const float4*)xr;
  const float4 b = *(const float4*)(xr + 4);
  float v[8] = {a.x, a.y, a.z, a.w, b.x, b.y, b.z, b.w};
  float s1 = 0.f, s2 = 0.f;
#pragma unroll
  for (int i = 0; i < 8; ++i) { s1 += v[i]; s2 += v[i] * v[i]; }
  s1 = wave_allsum(s1);
  s2 = wave_allsum(s2);
  const float mean = s1 * (1.0f / 512.0f);
  const float var = s2 * (1.0f / 512.0f) - mean * mean;
  const float inv = rsqrtf(var + 1e-5f);
  const float4 w1 = *(const float4*)(w + lane * 8);
  const float4 w2 = *(const float4*)(w + lane * 8 + 4);
  const float wv[8] = {w1.x, w1.y, w1.z, w1.w, w2.x, w2.y, w2.z, w2.w};
  short8 o8;
#pragma unroll
  for (int i = 0; i < 8; ++i) o8[i] = f2sb((v[i] - mean) * inv * wv[i]);
  *(short8*)(out + (long)row * 512 + lane * 8) = o8;
}

// pscan combine (Y-split form): q[t] = rmsnorm(Y1[t-d] + Y2[t]) for t >= d.
// Y layout: [t][0:512] = q@P1^T, [t][512:1024] = q@P2^T. One wave per row.
__global__ __launch_bounds__(256) void pscan_combine2(const bf16* __restrict__ Y,
                                                      bf16* __restrict__ QV, int d) {
  const int span = 4096 - d;
  const int wid = (blockIdx.x << 2) + (threadIdx.x >> 6);
  const int lane = threadIdx.x & 63;
  const int b = wid / span;
  const int tt = d + (wid - b * span);
  const long row2 = (long)b * 4096 + tt;
  const long row1 = row2 - d;
  const short8 a8 = *(const short8*)(Y + row1 * 1024 + lane * 8);
  const short8 b8 = *(const short8*)(Y + row2 * 1024 + 512 + lane * 8);
  float s[8]; float ss = 0.f;
#pragma unroll
  for (int i = 0; i < 8; ++i) {
    const float v = sb2f(a8[i]) + sb2f(b8[i]);
    s[i] = v; ss += v * v;
  }
  ss = wave_allsum(ss);
  const float inv = rsqrtf(ss * (1.0f / 512.0f) + 1e-6f);
  short8 o8;
#pragma unroll
  for (int i = 0; i < 8; ++i) o8[i] = f2sb(s[i] * inv);
  *(short8*)(QV + row2 * 1024 + lane * 8) = o8;
}

// u = q * v elementwise, 8 elems/thread.
__global__ __launch_bounds__(256) void qv_mul(const bf16* __restrict__ QV,
                                              bf16* __restrict__ u) {
  const long base = ((long)blockIdx.x * 256 + threadIdx.x) << 3;
  const long row = base >> 9;
  const int c = (int)(base & 511);
  const short8 q8 = *(const short8*)(QV + row * 1024 + c);
  const short8 v8 = *(const short8*)(QV + row * 1024 + 512 + c);
  short8 o8;
#pragma unroll
  for (int i = 0; i < 8; ++i) o8[i] = f2sb(sb2f(q8[i]) * sb2f(v8[i]));
  *(short8*)(u + row * 512 + c) = o8;
}

// ---------------------------------------------------------------------------
extern "C" void kernel_launch(void* const* d_in, const int* in_sizes, int n_in,
                              void* d_out, int out_size, void* d_ws, size_t ws_size,
                              hipStream_t stream) {
  (void)in_sizes; (void)n_in; (void)out_size; (void)ws_size;
  const float* x    = (const float*)d_in[0];
  const float* ln1w = (const float*)d_in[1];
  const float* Wq   = (const float*)d_in[2];
  const float* Wv   = (const float*)d_in[3];
  const float* Wo   = (const float*)d_in[4];
  // d_in[5] = identity: provably unused (positions t<d are never updated)
  const float* Wp1  = (const float*)d_in[6];
  const float* Wp2  = (const float*)d_in[7];
  const float* ln2w = (const float*)d_in[8];
  const float* Wfc  = (const float*)d_in[9];
  const float* Wpr  = (const float*)d_in[10];
  float* out = (float*)d_out;

  const long M = 16384;
  char* ws = (char*)d_ws;
  size_t off = 0;
  auto alloc = [&](size_t bytes) -> void* {
    void* p = ws + off;
    off += (bytes + 255) & ~(size_t)255;
    return p;
  };
  bf16* YZ   = (bf16*)alloc(M * 1024 * 2);   // Y (32MB); +QV = h3 (64MB)
  bf16* QV   = (bf16*)alloc(M * 1024 * 2);   // 32MB [q|v]
  bf16* hb   = (bf16*)alloc(M * 512 * 2);    // h -> u -> h2
  bf16* Wqvb = (bf16*)alloc(1024 * 512 * 2);
  bf16* Wob  = (bf16*)alloc(512 * 512 * 2);
  bf16* Wfcb = (bf16*)alloc(2048 * 512 * 2);
  bf16* Wprb = (bf16*)alloc(512 * 2048 * 2);
  float* Xf  = (float*)alloc(2 * 262144 * 4);
  bf16* Xhi  = (bf16*)alloc(2 * 262144 * 2);  // final [P1;P2] bf16 (1024x512)
  bf16* Xlo  = (bf16*)alloc(2 * 262144 * 2);
  bf16* XtAh = (bf16*)alloc(2 * 262144 * 2);
  bf16* XtAl = (bf16*)alloc(2 * 262144 * 2);
  bf16* XtBh = (bf16*)alloc(2 * 262144 * 2);
  bf16* XtBl = (bf16*)alloc(2 * 262144 * 2);
  bf16* Ghi  = (bf16*)alloc(2 * 262144 * 2);
  bf16* Glo  = (bf16*)alloc(2 * 262144 * 2);
  float* sig = (float*)alloc(256);
  bf16* Y  = YZ;   // [16384][1024] bf16, 32MB
  bf16* h3 = YZ;   // [16384,2048] bf16 spans YZ+QV (both dead by then)

  const auto Z0 = nullptr;

  // --- polar decomposition of Wp1, Wp2 (batched Newton-Schulz, split-bf16,
  //     3-buffer pipelined small GEMM)
  hipMemsetAsync(sig, 0, 2 * sizeof(float), stream);
  fnorm<<<512, 256, 0, stream>>>(Wp1, Wp2, sig);
  scale_init<<<2048, 256, 0, stream>>>(Wp1, Wp2, sig, Xf, Xhi, Xlo, XtAh, XtAl);

  bf16 *tch = XtAh, *tcl = XtAl, *tnh = XtBh, *tnl = XtBl;
  const long Sz = 262144;
  for (int i = 0; i < 20; ++i) {
    const bool pol = (i >= 16);          // 16 doublings + 4 polish
    const float ac = pol ? 1.5f : 2.0f;
    const float bc = pol ? -0.5f : -1.0f;
    dim3 g(8, 8, 2);
    gemm_ns<3><<<g, 256, 98304, stream>>>(
        Xhi, Xlo, Xhi, Xlo, Sz, Sz, Sz, 0.f, 0.f, Z0, Ghi, Glo, Z0, Z0);
    gemm_ns<4><<<g, 256, 98304, stream>>>(
        Ghi, Glo, tch, tcl, Sz, Sz, Sz, ac, bc, Xf, Xhi, Xlo, tnh, tnl);
    bf16* sw;
    sw = tch; tch = tnh; tnh = sw;
    sw = tcl; tcl = tnl; tnl = sw;
  }

  // --- weight conversions to bf16 (one launch)
  convert_weights<<<2816, 256, 0, stream>>>(Wq, Wv, Wo, Wfc, Wpr, Wqvb, Wob, Wfcb, Wprb);

  // --- SSM branch
  ln_rows<<<4096, 256, 0, stream>>>(x, ln1w, hb);
  // [q|v] = h @ [Wq;Wv]^T   (M=16384, N=1024, K=512)
  gemm256<0, 256><<<dim3(64, 4), 512, 131072, stream>>>(
      hb, Wqvb, 512, 512, 512, QV, 1024, Z0, Z0);

  for (int d = 1; d < 4096; d <<= 1) {
    // Y = q @ [P1;P2]^T  (M=16384, N=1024, K=512; B = Xhi directly)
    gemm256<0, 256><<<dim3(64, 4), 512, 131072, stream>>>(
        QV, Xhi, 512, 1024, 512, Y, 1024, Z0, Z0);
    // q[t] = rmsnorm(Y1[t-d] + Y2[t]) for t >= d
    pscan_combine2<<<4096 - d, 256, 0, stream>>>(Y, QV, d);
  }

  qv_mul<<<4096, 256, 0, stream>>>(QV, hb);  // u -> hb
  // x2 = x + u @ Wo^T  -> d_out (fp32)  (N=512 -> BN=128 grid (64,4))
  gemm256<2, 128><<<dim3(64, 4), 512, 147456, stream>>>(
      hb, Wob, 512, 512, 512, Z0, 512, x, out);

  // --- MLP branch
  ln_rows<<<4096, 256, 0, stream>>>(out, ln2w, hb);  // h2 -> hb
  gemm256<1, 256><<<dim3(64, 8), 512, 131072, stream>>>(
      hb, Wfcb, 512, 512, 512, h3, 2048, Z0, Z0);
  gemm256<2, 128><<<dim3(64, 4), 512, 147456, stream>>>(
      h3, Wprb, 2048, 2048, 2048, Z0, 512, out, out);
}